// Round 3
// baseline (19.602 us; speedup 1.0000x reference)
//
#include <hip/hip_runtime.h>
#include <math.h>

// Problem dims (fixed by reference setup_inputs):
// input[n=4][c=16][a=256], difference_mat[n][b=256][a][3], relative_mask[n][b][a],
// W[d=16][c=16][r=8], radii[r=8]  ->  out[n][d][b]  (float32)
//
// Single fused kernel. out[n,d,b] = sum_{a,r} R[n,b,a,r] * P[n,d,r,a],
// P[n,d,r,a] = sum_c W[d,c,r] * input[n,c,a].
// Each thread owns one a; it computes its own P column (128 values) in
// registers (2048 FMA, W reads are wave-uniform scalar loads), then reuses it
// for BT=4 b values. No intermediate tensor, no second launch.
constexpr int N = 4, B = 256, A = 256, C = 16, D = 16, RR = 8;
constexpr int DR = D * RR;           // 128
constexpr int BT = 4;                // b-tile per block
constexpr float GAMMA = 6.125f;

__global__ __launch_bounds__(256) void se3_fused_all(
    const float* __restrict__ input, const float* __restrict__ diff,
    const float* __restrict__ mask, const float* __restrict__ W,
    const float* __restrict__ radii, float* __restrict__ out)
{
    const int blk = blockIdx.x;          // n*(B/BT) + bg
    const int n  = blk / (B / BT);
    const int b0 = (blk % (B / BT)) * BT;
    const int a  = threadIdx.x;
    const int lane = threadIdx.x & 63;
    const int wave = threadIdx.x >> 6;

    // Coalesced input column loads (L2-hot after first blocks).
    float x[C];
#pragma unroll
    for (int c = 0; c < C; ++c) x[c] = input[(n * C + c) * A + a];

    float rad[RR];
#pragma unroll
    for (int r = 0; r < RR; ++r) rad[r] = radii[r];   // uniform -> s_load

    // Phase 1: P column for this thread's a, fully in VGPRs.
    // preg[d*8+r] = sum_c W[d][c][r] * x[c].  W is wave-uniform -> SGPR.
    float preg[DR];
#pragma unroll
    for (int d = 0; d < D; ++d) {
        float acc[RR];
#pragma unroll
        for (int r = 0; r < RR; ++r) acc[r] = 0.f;
#pragma unroll
        for (int c = 0; c < C; ++c) {
            const float xc = x[c];
            const float* Wdc = W + (d * C + c) * RR;
#pragma unroll
            for (int r = 0; r < RR; ++r) acc[r] += Wdc[r] * xc;
        }
#pragma unroll
        for (int r = 0; r < RR; ++r) preg[d * RR + r] = acc[r];
    }

    __shared__ float lds[BT][4][D];      // reduce slab, one sync total

    // Phase 2: for each b in tile, Gaussian basis + d-contraction + reduce.
#pragma unroll
    for (int bi = 0; bi < BT; ++bi) {
        const int b = b0 + bi;
        const size_t nba = (size_t)(n * B + b) * A + a;
        const float* dp = diff + nba * 3;
        const float dx = dp[0], dy = dp[1], dz = dp[2];
        const float dist = sqrtf(dx * dx + dy * dy + dz * dz);
        const float m = mask[nba];

        float R[RR];
#pragma unroll
        for (int r = 0; r < RR; ++r) {
            const float t = dist - rad[r];
            R[r] = m * __expf(-GAMMA * t * t);
        }

        float acc[D];
#pragma unroll
        for (int d = 0; d < D; ++d) {
            float s = 0.f;
#pragma unroll
            for (int r = 0; r < RR; ++r) s += R[r] * preg[d * RR + r];
            acc[d] = s;
        }

        // Fold-reduce across 64 lanes: 4 halving xor steps distribute the 16
        // d-sums across lane groups; 2 more xor steps finish the 64-lane sum.
        {
            const bool hi32 = (lane & 32) != 0;
#pragma unroll
            for (int i = 0; i < 8; ++i) {
                float send = hi32 ? acc[i] : acc[i + 8];
                float recv = __shfl_xor(send, 32, 64);
                acc[i] = (hi32 ? acc[i + 8] : acc[i]) + recv;
            }
        }
        {
            const bool hi16 = (lane & 16) != 0;
#pragma unroll
            for (int i = 0; i < 4; ++i) {
                float send = hi16 ? acc[i] : acc[i + 4];
                float recv = __shfl_xor(send, 16, 64);
                acc[i] = (hi16 ? acc[i + 4] : acc[i]) + recv;
            }
        }
        {
            const bool hi8 = (lane & 8) != 0;
#pragma unroll
            for (int i = 0; i < 2; ++i) {
                float send = hi8 ? acc[i] : acc[i + 2];
                float recv = __shfl_xor(send, 8, 64);
                acc[i] = (hi8 ? acc[i + 2] : acc[i]) + recv;
            }
        }
        {
            const bool hi4 = (lane & 4) != 0;
            float send = hi4 ? acc[0] : acc[1];
            float recv = __shfl_xor(send, 4, 64);
            acc[0] = (hi4 ? acc[1] : acc[0]) + recv;
        }
        float v = acc[0];
        v += __shfl_xor(v, 1, 64);
        v += __shfl_xor(v, 2, 64);
        if ((lane & 3) == 0) lds[bi][wave][(lane >> 2) & 15] = v;
    }
    __syncthreads();

    if (threadIdx.x < BT * D) {
        const int bi = threadIdx.x / D;
        const int d  = threadIdx.x % D;
        const float s = lds[bi][0][d] + lds[bi][1][d] + lds[bi][2][d] + lds[bi][3][d];
        out[(n * D + d) * B + (b0 + bi)] = s;
    }
}

extern "C" void kernel_launch(void* const* d_in, const int* in_sizes, int n_in,
                              void* d_out, int out_size, void* d_ws, size_t ws_size,
                              hipStream_t stream) {
    const float* input = (const float*)d_in[0];   // [N][C][A]
    const float* diff  = (const float*)d_in[1];   // [N][B][A][3]
    const float* mask  = (const float*)d_in[2];   // [N][B][A]
    const float* W     = (const float*)d_in[3];   // [D][C][RR]
    const float* radii = (const float*)d_in[4];   // [RR]
    float* out = (float*)d_out;                   // [N][D][B]

    se3_fused_all<<<N * (B / BT), 256, 0, stream>>>(input, diff, mask, W, radii, out);
}

// Round 4
// 17.609 us; speedup vs baseline: 1.1131x; 1.1131x over previous
//
#include <hip/hip_runtime.h>
#include <math.h>

// Problem dims (fixed by reference setup_inputs):
// input[n=4][c=16][a=256], difference_mat[n][b=256][a][3], relative_mask[n][b][a],
// W[d=16][c=16][r=8], radii[r=8]  ->  out[n][d][b]  (float32)
//
// Two-stage factored algorithm:
//   P[n][a][d*8+r] = sum_c W[d][c][r] * input[n][c][a]     (transposed layout)
//   out[n][d][b]   = sum_{a,r} mask[n,b,a]*exp(-G*(dist-radii[r])^2) * P[n][a][d*8+r]
constexpr int N = 4, B = 256, A = 256, C = 16, D = 16, RR = 8;
constexpr int DR = D * RR;           // 128
constexpr int BT = 4;                // b-tile per block in stage 2
constexpr float GAMMA = 6.125f;

// Stage 1: P[n][a][dr], thread = (a-pair, dr). Writes are tid-contiguous
// (fully coalesced dwords); input reads are broadcast within each half-block.
__global__ __launch_bounds__(256) void se3_compute_P(
    const float* __restrict__ input, const float* __restrict__ W,
    float* __restrict__ P)
{
    const int blk = blockIdx.x;            // n*(A/2) + a2
    const int n  = blk >> 7;
    const int a2 = blk & 127;
    const int al = threadIdx.x >> 7;       // 0..1
    const int dr = threadIdx.x & 127;      // 0..127
    const int a  = a2 * 2 + al;
    const int d  = dr >> 3;
    const int r  = dr & 7;

    float s = 0.f;
#pragma unroll
    for (int c = 0; c < C; ++c) {
        s += W[(d * C + c) * RR + r] * input[(n * C + c) * A + a];
    }
    P[((size_t)(n * A) + a) * DR + dr] = s;
}

// Stage 2: block = (n, 4 consecutive b), 512 threads = (h, a) with h the
// dr-half. Each thread holds 64 contiguous P floats (16x dwordx4), computes
// d in [8h, 8h+8), fold-reduces 8 values over 64 lanes (7 shfl + 3 xor).
__global__ __launch_bounds__(512) void se3_compute_out(
    const float* __restrict__ P, const float* __restrict__ diff,
    const float* __restrict__ mask, const float* __restrict__ radii,
    float* __restrict__ out)
{
    const int blk = blockIdx.x;            // n*(B/BT) + bg
    const int n  = blk / (B / BT);
    const int b0 = (blk % (B / BT)) * BT;
    const int h  = threadIdx.x >> 8;       // dr-half: 0..1
    const int a  = threadIdx.x & 255;
    const int lane = threadIdx.x & 63;
    const int wave = threadIdx.x >> 6;     // 0..7  (h = wave>>2)

    float rad[RR];
#pragma unroll
    for (int r = 0; r < RR; ++r) rad[r] = radii[r];   // uniform -> s_load

    // 64 contiguous P values for (n, a, h*64 .. h*64+63): 16x dwordx4.
    float preg[DR / 2];
    const float* Pt = P + ((size_t)(n * A) + a) * DR + h * (DR / 2);
#pragma unroll
    for (int j = 0; j < DR / 2; ++j) preg[j] = Pt[j];

    __shared__ float lds[BT][8][8];        // [bi][wave][d_local]

#pragma unroll
    for (int bi = 0; bi < BT; ++bi) {
        const int b = b0 + bi;
        const size_t nba = (size_t)(n * B + b) * A + a;
        const float* dp = diff + nba * 3;
        const float dx = dp[0], dy = dp[1], dz = dp[2];
        const float dist = sqrtf(dx * dx + dy * dy + dz * dz);
        const float m = mask[nba];

        float R[RR];
#pragma unroll
        for (int r = 0; r < RR; ++r) {
            const float t = dist - rad[r];
            R[r] = m * __expf(-GAMMA * t * t);
        }

        // acc[dl] for d = h*8 + dl
        float acc[8];
#pragma unroll
        for (int dl = 0; dl < 8; ++dl) {
            float s = 0.f;
#pragma unroll
            for (int r = 0; r < RR; ++r) s += R[r] * preg[dl * RR + r];
            acc[dl] = s;
        }

        // Fold-reduce 8 values over 64 lanes: 3 halving xor steps distribute
        // d_local across lane bits {5,4,3}; 3 scalar xor steps finish.
        {
            const bool hi = (lane & 32) != 0;
#pragma unroll
            for (int i = 0; i < 4; ++i) {
                float send = hi ? acc[i] : acc[i + 4];
                float recv = __shfl_xor(send, 32, 64);
                acc[i] = (hi ? acc[i + 4] : acc[i]) + recv;
            }
        }
        {
            const bool hi = (lane & 16) != 0;
#pragma unroll
            for (int i = 0; i < 2; ++i) {
                float send = hi ? acc[i] : acc[i + 2];
                float recv = __shfl_xor(send, 16, 64);
                acc[i] = (hi ? acc[i + 2] : acc[i]) + recv;
            }
        }
        {
            const bool hi = (lane & 8) != 0;
            float send = hi ? acc[0] : acc[1];
            float recv = __shfl_xor(send, 8, 64);
            acc[0] = (hi ? acc[1] : acc[0]) + recv;
        }
        float v = acc[0];
        v += __shfl_xor(v, 1, 64);
        v += __shfl_xor(v, 2, 64);
        v += __shfl_xor(v, 4, 64);
        // lane with (lane&7)==0 holds sum for d_local = (lane>>3)&7
        if ((lane & 7) == 0) lds[bi][wave][(lane >> 3) & 7] = v;
    }
    __syncthreads();

    if (threadIdx.x < BT * D) {
        const int bi = threadIdx.x >> 4;
        const int d  = threadIdx.x & 15;
        const int hh = d >> 3;             // contributing wave group
        const int dl = d & 7;
        const float s = lds[bi][hh * 4 + 0][dl] + lds[bi][hh * 4 + 1][dl]
                      + lds[bi][hh * 4 + 2][dl] + lds[bi][hh * 4 + 3][dl];
        out[(n * D + d) * B + (b0 + bi)] = s;
    }
}

// Fallback (only if ws too small): fully fused, recomputes the c-contraction
// per (n,b,a) with W staged in LDS.
__global__ __launch_bounds__(256) void se3_fused(
    const float* __restrict__ input, const float* __restrict__ diff,
    const float* __restrict__ mask, const float* __restrict__ W,
    const float* __restrict__ radii, float* __restrict__ out)
{
    const int blk = blockIdx.x;          // n*B + b
    const int n = blk / B;
    const int b = blk % B;
    const int a = threadIdx.x;

    __shared__ float Wl[D * C * RR];     // 8 KB
    for (int i = threadIdx.x; i < D * C * RR; i += 256) Wl[i] = W[i];
    __syncthreads();

    const size_t nba = (size_t)(n * B + b) * A + a;
    const float* dp = diff + nba * 3;
    const float dx = dp[0], dy = dp[1], dz = dp[2];
    const float dist = sqrtf(dx * dx + dy * dy + dz * dz);
    const float m = mask[nba];

    float R[RR];
#pragma unroll
    for (int r = 0; r < RR; ++r) {
        const float t = dist - radii[r];
        R[r] = m * __expf(-GAMMA * t * t);
    }

    float acc[D];
#pragma unroll
    for (int d = 0; d < D; ++d) acc[d] = 0.f;
    for (int c = 0; c < C; ++c) {
        const float x = input[(n * C + c) * A + a];
        float xr[RR];
#pragma unroll
        for (int r = 0; r < RR; ++r) xr[r] = x * R[r];
#pragma unroll
        for (int d = 0; d < D; ++d) {
#pragma unroll
            for (int r = 0; r < RR; ++r)
                acc[d] += Wl[(d * C + c) * RR + r] * xr[r];
        }
    }

    __shared__ float lds2[4 * D];
    const int lane = threadIdx.x & 63;
    const int wave = threadIdx.x >> 6;
#pragma unroll
    for (int d = 0; d < D; ++d) {
        float v = acc[d];
#pragma unroll
        for (int off = 32; off > 0; off >>= 1)
            v += __shfl_down(v, off, 64);
        if (lane == 0) lds2[wave * D + d] = v;
    }
    __syncthreads();
    if (threadIdx.x < D) {
        const int d = threadIdx.x;
        const float s = lds2[d] + lds2[D + d] + lds2[2 * D + d] + lds2[3 * D + d];
        out[(n * D + d) * B + b] = s;
    }
}

extern "C" void kernel_launch(void* const* d_in, const int* in_sizes, int n_in,
                              void* d_out, int out_size, void* d_ws, size_t ws_size,
                              hipStream_t stream) {
    const float* input = (const float*)d_in[0];   // [N][C][A]
    const float* diff  = (const float*)d_in[1];   // [N][B][A][3]
    const float* mask  = (const float*)d_in[2];   // [N][B][A]
    const float* W     = (const float*)d_in[3];   // [D][C][RR]
    const float* radii = (const float*)d_in[4];   // [RR]
    float* out = (float*)d_out;                   // [N][D][B]

    const size_t needP = (size_t)N * A * DR * sizeof(float);  // 512 KB
    if (ws_size >= needP) {
        float* P = (float*)d_ws;
        se3_compute_P<<<N * (A / 2), 256, 0, stream>>>(input, W, P);
        se3_compute_out<<<N * (B / BT), 512, 0, stream>>>(P, diff, mask, radii, out);
    } else {
        se3_fused<<<N * B, 256, 0, stream>>>(input, diff, mask, W, radii, out);
    }
}

// Round 5
// 14.985 us; speedup vs baseline: 1.3081x; 1.1751x over previous
//
#include <hip/hip_runtime.h>
#include <math.h>

// Problem dims (fixed by reference setup_inputs):
// input[n=4][c=16][a=256], difference_mat[n][b=256][a][3], relative_mask[n][b][a],
// W[d=16][c=16][r=8], radii[r=8]  ->  out[n][d][b]  (float32)
//
// Two-stage factored algorithm:
//   P[n][dr4][a][0..3] = sum_c W[d][c][r] * input[n][c][a]   (dr = dr4*4+k, d=dr>>3, r=dr&7)
//   out[n][d][b]       = sum_{a,r} mask[n,b,a]*exp(-G*(dist-radii[r])^2) * P[n,d,r,a]
//
// P element = float4 over 4 consecutive dr, indexed by lane-consecutive a:
// stage-2 loads are 16 B/lane AND wave-coalesced (1 KB per instruction).
constexpr int N = 4, B = 256, A = 256, C = 16, D = 16, RR = 8;
constexpr int DR = D * RR;           // 128
constexpr int DR4 = DR / 4;          // 32
constexpr int BT = 4;                // b-tile per block in stage 2
constexpr float GAMMA = 6.125f;

// Stage 1: one block per (n, dr4); thread = a. W reads wave-uniform (scalar),
// input reads coalesced, one float4 store per thread (tid-contiguous).
__global__ __launch_bounds__(256) void se3_compute_P(
    const float* __restrict__ input, const float* __restrict__ W,
    float4* __restrict__ P4)
{
    const int blk = blockIdx.x;            // n*DR4 + dr4
    const int n   = blk >> 5;
    const int dr4 = blk & 31;
    const int d   = dr4 >> 1;
    const int rb  = (dr4 & 1) * 4;         // r base
    const int a   = threadIdx.x;

    float acc0 = 0.f, acc1 = 0.f, acc2 = 0.f, acc3 = 0.f;
#pragma unroll
    for (int c = 0; c < C; ++c) {
        const float x = input[(n * C + c) * A + a];
        const float* Wdc = W + (d * C + c) * RR + rb;   // uniform -> s_load
        acc0 += Wdc[0] * x;
        acc1 += Wdc[1] * x;
        acc2 += Wdc[2] * x;
        acc3 += Wdc[3] * x;
    }
    P4[(size_t)blk * A + a] = make_float4(acc0, acc1, acc2, acc3);
}

// Stage 2: block = (n, 4 consecutive b), 512 threads = (h, a) with h the
// dr-half. Thread loads its 64 P floats as 16 coalesced float4 (dr4 = h*16+j),
// computes d in [8h, 8h+8), fold-reduces 8 values over 64 lanes.
__global__ __launch_bounds__(512) void se3_compute_out(
    const float4* __restrict__ P4, const float* __restrict__ diff,
    const float* __restrict__ mask, const float* __restrict__ radii,
    float* __restrict__ out)
{
    const int blk = blockIdx.x;            // n*(B/BT) + bg
    const int n  = blk / (B / BT);
    const int b0 = (blk % (B / BT)) * BT;
    const int h  = threadIdx.x >> 8;       // dr-half: 0..1
    const int a  = threadIdx.x & 255;
    const int lane = threadIdx.x & 63;
    const int wave = threadIdx.x >> 6;     // 0..7  (h = wave>>2)

    float rad[RR];
#pragma unroll
    for (int r = 0; r < RR; ++r) rad[r] = radii[r];   // uniform -> s_load

    // 64 P floats for (n, dr in [h*64, h*64+64)), a: 16 coalesced float4 loads.
    float preg[DR / 2];
    const float4* Pt = P4 + ((size_t)(n * DR4) + h * 16) * A + a;
#pragma unroll
    for (int j = 0; j < 16; ++j) {
        const float4 v = Pt[(size_t)j * A];
        preg[j * 4 + 0] = v.x;
        preg[j * 4 + 1] = v.y;
        preg[j * 4 + 2] = v.z;
        preg[j * 4 + 3] = v.w;
    }

    __shared__ float lds[BT][8][8];        // [bi][wave][d_local]

#pragma unroll
    for (int bi = 0; bi < BT; ++bi) {
        const int b = b0 + bi;
        const size_t nba = (size_t)(n * B + b) * A + a;
        const float* dp = diff + nba * 3;
        const float dx = dp[0], dy = dp[1], dz = dp[2];
        const float dist = sqrtf(dx * dx + dy * dy + dz * dz);
        const float m = mask[nba];

        float R[RR];
#pragma unroll
        for (int r = 0; r < RR; ++r) {
            const float t = dist - rad[r];
            R[r] = m * __expf(-GAMMA * t * t);
        }

        // acc[dl] for d = h*8 + dl; preg[dl*8 + r] = P[n, d, r, a]
        float acc[8];
#pragma unroll
        for (int dl = 0; dl < 8; ++dl) {
            float s = 0.f;
#pragma unroll
            for (int r = 0; r < RR; ++r) s += R[r] * preg[dl * RR + r];
            acc[dl] = s;
        }

        // Fold-reduce 8 values over 64 lanes: 3 halving xor steps distribute
        // d_local across lane bits {5,4,3}; 3 scalar xor steps finish.
        {
            const bool hi = (lane & 32) != 0;
#pragma unroll
            for (int i = 0; i < 4; ++i) {
                float send = hi ? acc[i] : acc[i + 4];
                float recv = __shfl_xor(send, 32, 64);
                acc[i] = (hi ? acc[i + 4] : acc[i]) + recv;
            }
        }
        {
            const bool hi = (lane & 16) != 0;
#pragma unroll
            for (int i = 0; i < 2; ++i) {
                float send = hi ? acc[i] : acc[i + 2];
                float recv = __shfl_xor(send, 16, 64);
                acc[i] = (hi ? acc[i + 2] : acc[i]) + recv;
            }
        }
        {
            const bool hi = (lane & 8) != 0;
            float send = hi ? acc[0] : acc[1];
            float recv = __shfl_xor(send, 8, 64);
            acc[0] = (hi ? acc[1] : acc[0]) + recv;
        }
        float v = acc[0];
        v += __shfl_xor(v, 1, 64);
        v += __shfl_xor(v, 2, 64);
        v += __shfl_xor(v, 4, 64);
        // lane with (lane&7)==0 holds sum for d_local = (lane>>3)&7
        if ((lane & 7) == 0) lds[bi][wave][(lane >> 3) & 7] = v;
    }
    __syncthreads();

    if (threadIdx.x < BT * D) {
        const int bi = threadIdx.x >> 4;
        const int d  = threadIdx.x & 15;
        const int hh = d >> 3;             // contributing wave group
        const int dl = d & 7;
        const float s = lds[bi][hh * 4 + 0][dl] + lds[bi][hh * 4 + 1][dl]
                      + lds[bi][hh * 4 + 2][dl] + lds[bi][hh * 4 + 3][dl];
        out[(n * D + d) * B + (b0 + bi)] = s;
    }
}

// Fallback (only if ws too small): fully fused, recomputes the c-contraction
// per (n,b,a) with W staged in LDS.
__global__ __launch_bounds__(256) void se3_fused(
    const float* __restrict__ input, const float* __restrict__ diff,
    const float* __restrict__ mask, const float* __restrict__ W,
    const float* __restrict__ radii, float* __restrict__ out)
{
    const int blk = blockIdx.x;          // n*B + b
    const int n = blk / B;
    const int b = blk % B;
    const int a = threadIdx.x;

    __shared__ float Wl[D * C * RR];     // 8 KB
    for (int i = threadIdx.x; i < D * C * RR; i += 256) Wl[i] = W[i];
    __syncthreads();

    const size_t nba = (size_t)(n * B + b) * A + a;
    const float* dp = diff + nba * 3;
    const float dx = dp[0], dy = dp[1], dz = dp[2];
    const float dist = sqrtf(dx * dx + dy * dy + dz * dz);
    const float m = mask[nba];

    float R[RR];
#pragma unroll
    for (int r = 0; r < RR; ++r) {
        const float t = dist - radii[r];
        R[r] = m * __expf(-GAMMA * t * t);
    }

    float acc[D];
#pragma unroll
    for (int d = 0; d < D; ++d) acc[d] = 0.f;
    for (int c = 0; c < C; ++c) {
        const float x = input[(n * C + c) * A + a];
        float xr[RR];
#pragma unroll
        for (int r = 0; r < RR; ++r) xr[r] = x * R[r];
#pragma unroll
        for (int d = 0; d < D; ++d) {
#pragma unroll
            for (int r = 0; r < RR; ++r)
                acc[d] += Wl[(d * C + c) * RR + r] * xr[r];
        }
    }

    __shared__ float lds2[4 * D];
    const int lane = threadIdx.x & 63;
    const int wave = threadIdx.x >> 6;
#pragma unroll
    for (int d = 0; d < D; ++d) {
        float v = acc[d];
#pragma unroll
        for (int off = 32; off > 0; off >>= 1)
            v += __shfl_down(v, off, 64);
        if (lane == 0) lds2[wave * D + d] = v;
    }
    __syncthreads();
    if (threadIdx.x < D) {
        const int d = threadIdx.x;
        const float s = lds2[d] + lds2[D + d] + lds2[2 * D + d] + lds2[3 * D + d];
        out[(n * D + d) * B + b] = s;
    }
}

extern "C" void kernel_launch(void* const* d_in, const int* in_sizes, int n_in,
                              void* d_out, int out_size, void* d_ws, size_t ws_size,
                              hipStream_t stream) {
    const float* input = (const float*)d_in[0];   // [N][C][A]
    const float* diff  = (const float*)d_in[1];   // [N][B][A][3]
    const float* mask  = (const float*)d_in[2];   // [N][B][A]
    const float* W     = (const float*)d_in[3];   // [D][C][RR]
    const float* radii = (const float*)d_in[4];   // [RR]
    float* out = (float*)d_out;                   // [N][D][B]

    const size_t needP = (size_t)N * DR * A * sizeof(float);  // 512 KB
    if (ws_size >= needP) {
        float4* P4 = (float4*)d_ws;
        se3_compute_P<<<N * DR4, 256, 0, stream>>>(input, W, P4);
        se3_compute_out<<<N * (B / BT), 512, 0, stream>>>(P4, diff, mask, radii, out);
    } else {
        se3_fused<<<N * B, 256, 0, stream>>>(input, diff, mask, W, radii, out);
    }
}